// Round 10
// baseline (231.919 us; speedup 1.0000x reference)
//
#include <hip/hip_runtime.h>
#include <math.h>

#define NATOM_FEAT 24   // IPSIN * NWAVE = 3*8
#define PORI 13
#define NW 8
#define HID 128
#define CH 128          // edges staged per LDS chunk
#define KA 8            // atoms per block
#define SCAN_T 1024

__global__ void zero_k(int* __restrict__ p, int n)
{
    int i = blockIdx.x * blockDim.x + threadIdx.x;
    if (i < n) p[i] = 0;
}

// ---------------- CSR build ----------------
__global__ void csr_count(const int* __restrict__ nl, int* __restrict__ counts, int E)
{
    int e = blockIdx.x * blockDim.x + threadIdx.x;
    if (e < E) atomicAdd(&counts[nl[e]], 1);
}

// scan counts -> rowptr, re-zero counts (reused as fill cursor)
__global__ void csr_scan(int* __restrict__ counts, int* __restrict__ rowptr, int A)
{
    __shared__ int lds[SCAN_T];
    int tid = threadIdx.x;
    int chunk = (A + SCAN_T - 1) / SCAN_T;
    int base = tid * chunk;
    int own = 0;
    for (int i = 0; i < chunk; ++i) {
        int idx = base + i;
        if (idx < A) own += counts[idx];
    }
    lds[tid] = own;
    __syncthreads();
    for (int off = 1; off < SCAN_T; off <<= 1) {
        int v = (tid >= off) ? lds[tid - off] : 0;
        __syncthreads();
        lds[tid] += v;
        __syncthreads();
    }
    int running = lds[tid] - own;
    for (int i = 0; i < chunk; ++i) {
        int idx = base + i;
        if (idx < A) {
            rowptr[idx] = running;
            running += counts[idx];
            counts[idx] = 0;
        }
    }
    if (tid == SCAN_T - 1) rowptr[A] = lds[SCAN_T - 1];
}

// scatter: ONE 16B write per edge {dx,dy,dz, n-as-float-bits}
__global__ void csr_fill(const int* __restrict__ nl, const int* __restrict__ rowptr,
                         int* __restrict__ cursor,
                         const float* __restrict__ cart,
                         const float* __restrict__ shifts,
                         float4* __restrict__ geom,
                         int E)
{
    int e = blockIdx.x * blockDim.x + threadIdx.x;
    if (e >= E) return;
    int c = nl[e];
    int n = nl[E + e];
    float dx = cart[3*c+0] - cart[3*n+0] - shifts[3*e+0];
    float dy = cart[3*c+1] - cart[3*n+1] - shifts[3*e+1];
    float dz = cart[3*c+2] - cart[3*n+2] - shifts[3*e+2];
    int ofs  = atomicAdd(&cursor[c], 1);
    int slot = rowptr[c] + ofs;
    geom[slot] = make_float4(dx, dy, dz, __int_as_float(n));
}

// slot-major: contiguous read of geom, contiguous write of fc-folded gaussians
__global__ void gauss_k(const float4* __restrict__ geom,
                        const int* __restrict__ species,
                        const float* __restrict__ g_rs,
                        const float* __restrict__ g_inta,
                        const float* __restrict__ g_par,
                        float4* __restrict__ gauss,   // [2E] = [E][8] floats
                        int E)
{
    __shared__ float s_rs[32], s_in[32], s_pa[32];
    int tid = threadIdx.x;
    if (tid < 32) {
        s_rs[tid] = g_rs[tid];
        s_in[tid] = g_inta[tid];
        s_pa[tid] = g_par[tid];
    }
    __syncthreads();
    int s = blockIdx.x * blockDim.x + tid;
    if (s >= E) return;
    float4 G = geom[s];
    float r = sqrtf(G.x*G.x + G.y*G.y + G.z*G.z);
    float fcb = 0.5f * cosf(r * 0.6283185307179586f) + 0.5f;   // pi/5
    float fc  = fcb * fcb;
    int sb = species[__float_as_int(G.w)] * NW;
    float g[NW];
    #pragma unroll
    for (int w = 0; w < NW; ++w) {
        float dr = r - s_rs[sb + w];
        g[w] = __expf(-s_in[sb + w] * dr * dr) * s_pa[sb + w] * fc;
    }
    gauss[2*s+0] = make_float4(g[0], g[1], g[2], g[3]);
    gauss[2*s+1] = make_float4(g[4], g[5], g[6], g[7]);
}

// ---------------- fused multi-atom pass (+ optional MLP epilogue) ----------------
// KA=8 atoms per 128-thread block; their CSR slots are one contiguous range.
// [edge][feat] LDS tiles: inner-loop reads are bank-conflict-free broadcasts.
// Tail phases alias the chunk LDS (dead after the K-loop).
template<bool HASOUT, bool MLP>
__global__ __launch_bounds__(128)
void atom_pass(const float4* __restrict__ geom,
               const float* __restrict__ gauss8,   // [E*8], fc-folded
               const int* __restrict__ rowptr,
               const float* __restrict__ outp_in,  // [A,24] if HASOUT
               const float* __restrict__ w1, const float* __restrict__ b1,
               const float* __restrict__ w2, const float* __restrict__ b2,
               float* __restrict__ out,            // [A,24]: mlp out (MLP) or density
               int A)
{
    __shared__ __align__(16) float smem[CH * (PORI + NATOM_FEAT)];   // 4736 floats = 18.5 KB
    float* ls_ang = smem;                     // [CH][13], used in K-loop
    float* ls_og  = smem + CH * PORI;         // [CH][24], used in K-loop
    // tail aliases (K-loop LDS dead by then):
    float* orb_s = smem;                      // [KA][104]
    float* dvec  = smem + KA * (PORI * NW);   // [KA][24]
    float* t_s   = dvec + KA * NATOM_FEAT;    // [KA][129]

    int tid = threadIdx.x;
    int a0 = blockIdx.x * KA;

    int f = tid;                     // f = p*8 + w, valid for f < 104
    int p = f >> 3, w = f & 7;
    int ip = (p == 0) ? 0 : ((p < 4) ? 1 : 2);
    int ogidx = ip * NW + w;

    // per-block row pointers (wave-uniform -> scalar regs, uniform branches)
    int rb[KA + 1];
    #pragma unroll
    for (int k = 0; k <= KA; ++k) rb[k] = rowptr[min(a0 + k, A)];

    // phase-B weight column: identical for all KA atoms, load once
    float w1r[NATOM_FEAT], b1r = 0.0f;
    if (MLP) {
        b1r = b1[tid];
        #pragma unroll
        for (int j = 0; j < NATOM_FEAT; ++j) w1r[j] = w1[j * HID + tid];
    }

    float acc[KA];
    #pragma unroll
    for (int k = 0; k < KA; ++k) acc[k] = 0.0f;

    for (int s = rb[0]; s < rb[KA]; s += CH) {
        int m = min(CH, rb[KA] - s);
        if (tid < m) {
            float4 G = geom[s + tid];
            float ax = G.x, ay = G.y, az = G.z;
            float* ar = ls_ang + tid * PORI;
            ar[0]  = 1.0f;
            ar[1]  = ax;    ar[2]  = ay;    ar[3]  = az;
            ar[4]  = ax*ax; ar[5]  = ax*ay; ar[6]  = ax*az;
            ar[7]  = ay*ax; ar[8]  = ay*ay; ar[9]  = ay*az;
            ar[10] = az*ax; ar[11] = az*ay; ar[12] = az*az;
        }
        for (int idx = tid; idx < m * NATOM_FEAT; idx += 128) {
            int j = idx / NATOM_FEAT;          // const divisor -> magic mul
            int c = idx - j * NATOM_FEAT;
            float gg = gauss8[(size_t)(s + j) * NW + (c & 7)];
            if (HASOUT) {
                int n = __float_as_int(geom[s + j].w);   // L1-hit (line read above)
                gg *= outp_in[(size_t)n * NATOM_FEAT + c];
            }
            ls_og[j * NATOM_FEAT + c] = gg;
        }
        __syncthreads();
        if (f < PORI * NW) {
            #pragma unroll
            for (int k = 0; k < KA; ++k) {
                int lo = max(rb[k] - s, 0);
                int hi = min(rb[k+1] - s, m);
                for (int j = lo; j < hi; ++j)
                    acc[k] += ls_ang[j * PORI + p] * ls_og[j * NATOM_FEAT + ogidx];
            }
        }
        __syncthreads();
    }

    // orbital^2 for all KA atoms
    if (f < PORI * NW) {
        #pragma unroll
        for (int k = 0; k < KA; ++k) orb_s[k * (PORI * NW) + f] = acc[k] * acc[k];
    }
    __syncthreads();

    // density reduce: KA*24 = 192 tasks
    #pragma unroll
    for (int t = tid; t < KA * NATOM_FEAT; t += 128) {
        int k  = t / NATOM_FEAT;
        int iw = t - k * NATOM_FEAT;
        int i = iw >> 3, ww = iw & 7;
        const float* ob = orb_s + k * (PORI * NW);
        float sum;
        if (i == 0) {
            sum = ob[ww];
        } else if (i == 1) {
            sum = ob[NW + ww] + ob[2*NW + ww] + ob[3*NW + ww];
        } else {
            sum = 0.0f;
            #pragma unroll
            for (int q = 4; q < PORI; ++q) sum += ob[q*NW + ww];
        }
        if (MLP) dvec[t] = sum;
        else if (a0 + k < A) out[(size_t)(a0 + k) * NATOM_FEAT + iw] = sum;
    }

    if (MLP) {
        __syncthreads();
        // phase B: lane = hidden unit h, loop atoms; dvec reads are broadcasts
        #pragma unroll
        for (int k = 0; k < KA; ++k) {
            float hacc = b1r;
            #pragma unroll
            for (int j = 0; j < NATOM_FEAT; ++j) hacc += dvec[k * NATOM_FEAT + j] * w1r[j];
            float e = __expf(2.0f * hacc);
            t_s[k * (HID + 1) + tid] = 1.0f - 2.0f / (e + 1.0f);   // tanh
        }
        __syncthreads();
        // phase C: KA*24 = 192 tasks; w2 reads L1-hot, t_s stride-129 conflict-free
        #pragma unroll
        for (int t = tid; t < KA * NATOM_FEAT; t += 128) {
            int k = t / NATOM_FEAT;
            int j = t - k * NATOM_FEAT;
            float o = b2[j];
            #pragma unroll 8
            for (int h = 0; h < HID; ++h) o += t_s[k * (HID + 1) + h] * w2[h * NATOM_FEAT + j];
            if (a0 + k < A) out[(size_t)(a0 + k) * NATOM_FEAT + j] = o;
        }
    }
}

extern "C" void kernel_launch(void* const* d_in, const int* in_sizes, int n_in,
                              void* d_out, int out_size, void* d_ws, size_t ws_size,
                              hipStream_t stream)
{
    const float* cart    = (const float*)d_in[0];
    const int*   nl      = (const int*)d_in[1];
    const float* shifts  = (const float*)d_in[2];
    const int*   species = (const int*)d_in[3];
    const float* rs      = (const float*)d_in[4];
    const float* inta    = (const float*)d_in[5];
    const float* params  = (const float*)d_in[6];
    const float* w1_0 = (const float*)d_in[7];
    const float* b1_0 = (const float*)d_in[8];
    const float* w2_0 = (const float*)d_in[9];
    const float* b2_0 = (const float*)d_in[10];
    const float* w1_1 = (const float*)d_in[11];
    const float* b1_1 = (const float*)d_in[12];
    const float* w2_1 = (const float*)d_in[13];
    const float* b2_1 = (const float*)d_in[14];

    const int A = in_sizes[0] / 3;
    const int E = in_sizes[1] / 2;

    // workspace layout — 16B-aligned arrays first
    char* ws = (char*)d_ws;
    float4* geom  = (float4*)ws;              ws += (size_t)E * 16;
    float4* gauss = (float4*)ws;              ws += (size_t)E * 32;
    int*   counts = (int*)ws;                 ws += (size_t)A * 4;
    int*   rowptr = (int*)ws;                 ws += (size_t)(A + 1) * 4;
    float* outpA  = (float*)ws;               ws += (size_t)A * NATOM_FEAT * 4;
    float* outpB  = (float*)ws;               ws += (size_t)A * NATOM_FEAT * 4;
    float* dout   = (float*)d_out;

    const int BLK = 256;
    const int gridE = (E + BLK - 1) / BLK;
    const int gridA = (A + BLK - 1) / BLK;
    const int gridP = (A + KA - 1) / KA;

    // ---- CSR build + per-edge precompute (once) ----
    zero_k<<<gridA, BLK, 0, stream>>>(counts, A);
    csr_count<<<gridE, BLK, 0, stream>>>(nl, counts, E);
    csr_scan<<<1, SCAN_T, 0, stream>>>(counts, rowptr, A);
    csr_fill<<<gridE, BLK, 0, stream>>>(nl, rowptr, counts, cart, shifts, geom, E);
    gauss_k<<<gridE, BLK, 0, stream>>>(geom, species, rs, inta, params, gauss, E);

    // ---- pass 0 (+ MLP0) -> outpA ----
    atom_pass<false, true><<<gridP, 128, 0, stream>>>(geom, (const float*)gauss, rowptr,
                                                      nullptr, w1_0, b1_0, w2_0, b2_0, outpA, A);
    // ---- pass 1 (+ MLP1) -> outpB ----
    atom_pass<true, true><<<gridP, 128, 0, stream>>>(geom, (const float*)gauss, rowptr,
                                                     outpA, w1_1, b1_1, w2_1, b2_1, outpB, A);
    // ---- pass 2 (density only) -> d_out ----
    atom_pass<true, false><<<gridP, 128, 0, stream>>>(geom, (const float*)gauss, rowptr,
                                                      outpB, nullptr, nullptr, nullptr, nullptr, dout, A);
}

// Round 11
// 200.569 us; speedup vs baseline: 1.1563x; 1.1563x over previous
//
#include <hip/hip_runtime.h>
#include <math.h>

#define NATOM_FEAT 24   // IPSIN * NWAVE = 3*8
#define PORI 13
#define NW 8
#define HID 128
#define CH 64           // edges staged per LDS chunk
#define ANG_S 13        // ls_ang stride (odd -> conflict-free writes/reads)
#define OG_S 26         // ls_og stride (even -> 8B-aligned float2, 2-way free)
#define SCAN_T 1024

__global__ void zero_k(int* __restrict__ p, int n)
{
    int i = blockIdx.x * blockDim.x + threadIdx.x;
    if (i < n) p[i] = 0;
}

// ---------------- CSR build ----------------
__global__ void csr_count(const int* __restrict__ nl, int* __restrict__ counts, int E)
{
    int e = blockIdx.x * blockDim.x + threadIdx.x;
    if (e < E) atomicAdd(&counts[nl[e]], 1);
}

// scan counts -> rowptr, re-zero counts (reused as fill cursor)
__global__ void csr_scan(int* __restrict__ counts, int* __restrict__ rowptr, int A)
{
    __shared__ int lds[SCAN_T];
    int tid = threadIdx.x;
    int chunk = (A + SCAN_T - 1) / SCAN_T;
    int base = tid * chunk;
    int own = 0;
    for (int i = 0; i < chunk; ++i) {
        int idx = base + i;
        if (idx < A) own += counts[idx];
    }
    lds[tid] = own;
    __syncthreads();
    for (int off = 1; off < SCAN_T; off <<= 1) {
        int v = (tid >= off) ? lds[tid - off] : 0;
        __syncthreads();
        lds[tid] += v;
        __syncthreads();
    }
    int running = lds[tid] - own;
    for (int i = 0; i < chunk; ++i) {
        int idx = base + i;
        if (idx < A) {
            rowptr[idx] = running;
            running += counts[idx];
            counts[idx] = 0;
        }
    }
    if (tid == SCAN_T - 1) rowptr[A] = lds[SCAN_T - 1];
}

// scatter: ONE 16B write per edge {dx,dy,dz, n-as-float-bits}
__global__ void csr_fill(const int* __restrict__ nl, const int* __restrict__ rowptr,
                         int* __restrict__ cursor,
                         const float* __restrict__ cart,
                         const float* __restrict__ shifts,
                         float4* __restrict__ geom,
                         int E)
{
    int e = blockIdx.x * blockDim.x + threadIdx.x;
    if (e >= E) return;
    int c = nl[e];
    int n = nl[E + e];
    float dx = cart[3*c+0] - cart[3*n+0] - shifts[3*e+0];
    float dy = cart[3*c+1] - cart[3*n+1] - shifts[3*e+1];
    float dz = cart[3*c+2] - cart[3*n+2] - shifts[3*e+2];
    int ofs  = atomicAdd(&cursor[c], 1);
    int slot = rowptr[c] + ofs;
    geom[slot] = make_float4(dx, dy, dz, __int_as_float(n));
}

// slot-major: contiguous read of geom, contiguous write of fc-folded gaussians
__global__ void gauss_k(const float4* __restrict__ geom,
                        const int* __restrict__ species,
                        const float* __restrict__ g_rs,
                        const float* __restrict__ g_inta,
                        const float* __restrict__ g_par,
                        float4* __restrict__ gauss,   // [2E] = [E][8] floats
                        int E)
{
    __shared__ float s_rs[32], s_in[32], s_pa[32];
    int tid = threadIdx.x;
    if (tid < 32) {
        s_rs[tid] = g_rs[tid];
        s_in[tid] = g_inta[tid];
        s_pa[tid] = g_par[tid];
    }
    __syncthreads();
    int s = blockIdx.x * blockDim.x + tid;
    if (s >= E) return;
    float4 G = geom[s];
    float r = sqrtf(G.x*G.x + G.y*G.y + G.z*G.z);
    float fcb = 0.5f * cosf(r * 0.6283185307179586f) + 0.5f;   // pi/5
    float fc  = fcb * fcb;
    int sb = species[__float_as_int(G.w)] * NW;
    float g[NW];
    #pragma unroll
    for (int w = 0; w < NW; ++w) {
        float dr = r - s_rs[sb + w];
        g[w] = __expf(-s_in[sb + w] * dr * dr) * s_pa[sb + w] * fc;
    }
    gauss[2*s+0] = make_float4(g[0], g[1], g[2], g[3]);
    gauss[2*s+1] = make_float4(g[4], g[5], g[6], g[7]);
}

// ---------------- fused per-atom pass (+ optional MLP epilogue) ----------------
// Staging: one edge per lane, all-vector loads (1+2+6 float4), conflict-free LDS writes.
// Inner loop: bank-conflict-free broadcast reads, 1 FMA per (edge,feature).
template<bool HASOUT, bool MLP>
__global__ __launch_bounds__(128)
void atom_pass(const float4* __restrict__ geom,
               const float4* __restrict__ gauss4,  // [E][2] float4, fc-folded
               const int* __restrict__ rowptr,
               const float* __restrict__ outp_in,  // [A,24] if HASOUT
               const float* __restrict__ w1, const float* __restrict__ b1,
               const float* __restrict__ w2, const float* __restrict__ b2,
               float* __restrict__ out,            // [A,24]: mlp out (MLP) or density
               int A)
{
    __shared__ __align__(16) float smem[CH * (ANG_S + OG_S)];   // 64*39*4 = 9984 B
    float* ls_ang = smem;                 // [CH][13]
    float* ls_og  = smem + CH * ANG_S;    // [CH][26] (24 used)
    // tail aliases (K-loop LDS dead after last barrier):
    float* orb_s = smem;                  // [104]
    float* dvec  = smem + 104;            // [24]
    float* tvec  = smem + 128;            // [128]

    int tid = threadIdx.x;
    int a = blockIdx.x;
    int s0 = rowptr[a], s1 = rowptr[a+1];

    int f = tid;                     // f = p*8 + w, valid for f < 104
    int p = f >> 3, w = f & 7;
    int ip = (p == 0) ? 0 : ((p < 4) ? 1 : 2);
    int ogidx = ip * NW + w;

    // phase-B weight column: load once (independent of edge loop)
    float w1r[NATOM_FEAT], b1r = 0.0f;
    if (MLP) {
        b1r = b1[tid];
        #pragma unroll
        for (int j = 0; j < NATOM_FEAT; ++j) w1r[j] = w1[j * HID + tid];
    }

    float acc = 0.0f;

    for (int s = s0; s < s1; s += CH) {
        int m = min(CH, s1 - s);
        if (tid < m) {
            float4 G = gauss4[2*(s + tid)];
            float4 H = gauss4[2*(s + tid) + 1];
            float go[NW] = { G.x, G.y, G.z, G.w, H.x, H.y, H.z, H.w };
            float4 D = geom[s + tid];
            float ax = D.x, ay = D.y, az = D.z;

            float* ar = ls_ang + tid * ANG_S;
            ar[0]  = 1.0f;
            ar[1]  = ax;    ar[2]  = ay;    ar[3]  = az;
            ar[4]  = ax*ax; ar[5]  = ax*ay; ar[6]  = ax*az;
            ar[7]  = ay*ax; ar[8]  = ay*ay; ar[9]  = ay*az;
            ar[10] = az*ax; ar[11] = az*ay; ar[12] = az*az;

            float2* ogr = (float2*)(ls_og + tid * OG_S);
            if (HASOUT) {
                const float4* orow = (const float4*)(outp_in + (size_t)__float_as_int(D.w) * NATOM_FEAT);
                float4 o0 = orow[0], o1 = orow[1], o2 = orow[2];
                float4 o3 = orow[3], o4 = orow[4], o5 = orow[5];
                ogr[0]  = make_float2(go[0]*o0.x, go[1]*o0.y);
                ogr[1]  = make_float2(go[2]*o0.z, go[3]*o0.w);
                ogr[2]  = make_float2(go[4]*o1.x, go[5]*o1.y);
                ogr[3]  = make_float2(go[6]*o1.z, go[7]*o1.w);
                ogr[4]  = make_float2(go[0]*o2.x, go[1]*o2.y);
                ogr[5]  = make_float2(go[2]*o2.z, go[3]*o2.w);
                ogr[6]  = make_float2(go[4]*o3.x, go[5]*o3.y);
                ogr[7]  = make_float2(go[6]*o3.z, go[7]*o3.w);
                ogr[8]  = make_float2(go[0]*o4.x, go[1]*o4.y);
                ogr[9]  = make_float2(go[2]*o4.z, go[3]*o4.w);
                ogr[10] = make_float2(go[4]*o5.x, go[5]*o5.y);
                ogr[11] = make_float2(go[6]*o5.z, go[7]*o5.w);
            } else {
                #pragma unroll
                for (int cc = 0; cc < 12; ++cc)
                    ogr[cc] = make_float2(go[(2*cc) & 7], go[(2*cc+1) & 7]);
            }
        }
        __syncthreads();
        if (f < PORI * NW) {
            #pragma unroll 4
            for (int j = 0; j < m; ++j)
                acc += ls_ang[j * ANG_S + p] * ls_og[j * OG_S + ogidx];
        }
        __syncthreads();
    }

    // orbital^2 -> aliased LDS
    if (f < PORI * NW) orb_s[f] = acc * acc;
    __syncthreads();

    if (tid < NATOM_FEAT) {
        int i = tid >> 3, ww = tid & 7;
        float sum;
        if (i == 0) {
            sum = orb_s[ww];
        } else if (i == 1) {
            sum = orb_s[NW + ww] + orb_s[2*NW + ww] + orb_s[3*NW + ww];
        } else {
            sum = 0.0f;
            #pragma unroll
            for (int q = 4; q < PORI; ++q) sum += orb_s[q*NW + ww];
        }
        if (MLP) dvec[tid] = sum;
        else     out[(size_t)a * NATOM_FEAT + tid] = sum;
    }

    if (MLP) {
        __syncthreads();
        // phase B: 128 lanes = 128 hidden units; dvec reads are broadcasts
        float hacc = b1r;
        #pragma unroll
        for (int j = 0; j < NATOM_FEAT; ++j) hacc += dvec[j] * w1r[j];
        float e = __expf(2.0f * hacc);
        tvec[tid] = 1.0f - 2.0f / (e + 1.0f);   // tanh, saturates correctly
        __syncthreads();
        // phase C: 24 lanes = 24 outputs; w2 coalesced + L1-hot
        if (tid < NATOM_FEAT) {
            float o = b2[tid];
            #pragma unroll 8
            for (int h = 0; h < HID; ++h) o += tvec[h] * w2[h * NATOM_FEAT + tid];
            out[(size_t)a * NATOM_FEAT + tid] = o;
        }
    }
}

extern "C" void kernel_launch(void* const* d_in, const int* in_sizes, int n_in,
                              void* d_out, int out_size, void* d_ws, size_t ws_size,
                              hipStream_t stream)
{
    const float* cart    = (const float*)d_in[0];
    const int*   nl      = (const int*)d_in[1];
    const float* shifts  = (const float*)d_in[2];
    const int*   species = (const int*)d_in[3];
    const float* rs      = (const float*)d_in[4];
    const float* inta    = (const float*)d_in[5];
    const float* params  = (const float*)d_in[6];
    const float* w1_0 = (const float*)d_in[7];
    const float* b1_0 = (const float*)d_in[8];
    const float* w2_0 = (const float*)d_in[9];
    const float* b2_0 = (const float*)d_in[10];
    const float* w1_1 = (const float*)d_in[11];
    const float* b1_1 = (const float*)d_in[12];
    const float* w2_1 = (const float*)d_in[13];
    const float* b2_1 = (const float*)d_in[14];

    const int A = in_sizes[0] / 3;
    const int E = in_sizes[1] / 2;

    // workspace layout — 16B-aligned arrays first
    char* ws = (char*)d_ws;
    float4* geom  = (float4*)ws;              ws += (size_t)E * 16;
    float4* gauss = (float4*)ws;              ws += (size_t)E * 32;
    int*   counts = (int*)ws;                 ws += (size_t)A * 4;
    int*   rowptr = (int*)ws;                 ws += (size_t)(A + 1) * 4;
    float* outpA  = (float*)ws;               ws += (size_t)A * NATOM_FEAT * 4;
    float* outpB  = (float*)ws;               ws += (size_t)A * NATOM_FEAT * 4;
    float* dout   = (float*)d_out;

    const int BLK = 256;
    const int gridE = (E + BLK - 1) / BLK;
    const int gridA = (A + BLK - 1) / BLK;

    // ---- CSR build + per-edge precompute (once) ----
    zero_k<<<gridA, BLK, 0, stream>>>(counts, A);
    csr_count<<<gridE, BLK, 0, stream>>>(nl, counts, E);
    csr_scan<<<1, SCAN_T, 0, stream>>>(counts, rowptr, A);
    csr_fill<<<gridE, BLK, 0, stream>>>(nl, rowptr, counts, cart, shifts, geom, E);
    gauss_k<<<gridE, BLK, 0, stream>>>(geom, species, rs, inta, params, gauss, E);

    // ---- pass 0 (+ MLP0) -> outpA ----
    atom_pass<false, true><<<A, 128, 0, stream>>>(geom, gauss, rowptr,
                                                  nullptr, w1_0, b1_0, w2_0, b2_0, outpA, A);
    // ---- pass 1 (+ MLP1) -> outpB ----
    atom_pass<true, true><<<A, 128, 0, stream>>>(geom, gauss, rowptr,
                                                 outpA, w1_1, b1_1, w2_1, b2_1, outpB, A);
    // ---- pass 2 (density only) -> d_out ----
    atom_pass<true, false><<<A, 128, 0, stream>>>(geom, gauss, rowptr,
                                                  outpB, nullptr, nullptr, nullptr, nullptr, dout, A);
}

// Round 12
// 179.812 us; speedup vs baseline: 1.2898x; 1.1154x over previous
//
#include <hip/hip_runtime.h>
#include <math.h>

#define NATOM_FEAT 24   // IPSIN * NWAVE = 3*8
#define PORI 13
#define NW 8
#define HID 128
#define CH 48           // edges staged per LDS chunk (Poisson(25): 1 chunk ~always)
#define ANG_S 13        // ls_ang stride (odd -> conflict-free)
#define OG_S 26         // ls_og stride
#define SCAN_T 1024

__global__ void zero_k(int* __restrict__ p, int n)
{
    int i = blockIdx.x * blockDim.x + threadIdx.x;
    if (i < n) p[i] = 0;
}

// ---------------- CSR build ----------------
__global__ void csr_count(const int* __restrict__ nl, int* __restrict__ counts, int E)
{
    int e = blockIdx.x * blockDim.x + threadIdx.x;
    if (e < E) atomicAdd(&counts[nl[e]], 1);
}

// scan counts -> rowptr, re-zero counts (reused as fill cursor)
__global__ void csr_scan(int* __restrict__ counts, int* __restrict__ rowptr, int A)
{
    __shared__ int lds[SCAN_T];
    int tid = threadIdx.x;
    int chunk = (A + SCAN_T - 1) / SCAN_T;
    int base = tid * chunk;
    int own = 0;
    for (int i = 0; i < chunk; ++i) {
        int idx = base + i;
        if (idx < A) own += counts[idx];
    }
    lds[tid] = own;
    __syncthreads();
    for (int off = 1; off < SCAN_T; off <<= 1) {
        int v = (tid >= off) ? lds[tid - off] : 0;
        __syncthreads();
        lds[tid] += v;
        __syncthreads();
    }
    int running = lds[tid] - own;
    for (int i = 0; i < chunk; ++i) {
        int idx = base + i;
        if (idx < A) {
            rowptr[idx] = running;
            running += counts[idx];
            counts[idx] = 0;
        }
    }
    if (tid == SCAN_T - 1) rowptr[A] = lds[SCAN_T - 1];
}

// scatter: ONE 16B write per edge {dx,dy,dz, n-as-float-bits}
__global__ void csr_fill(const int* __restrict__ nl, const int* __restrict__ rowptr,
                         int* __restrict__ cursor,
                         const float* __restrict__ cart,
                         const float* __restrict__ shifts,
                         float4* __restrict__ geom,
                         int E)
{
    int e = blockIdx.x * blockDim.x + threadIdx.x;
    if (e >= E) return;
    int c = nl[e];
    int n = nl[E + e];
    float dx = cart[3*c+0] - cart[3*n+0] - shifts[3*e+0];
    float dy = cart[3*c+1] - cart[3*n+1] - shifts[3*e+1];
    float dz = cart[3*c+2] - cart[3*n+2] - shifts[3*e+2];
    int ofs  = atomicAdd(&cursor[c], 1);
    int slot = rowptr[c] + ofs;
    geom[slot] = make_float4(dx, dy, dz, __int_as_float(n));
}

// slot-major: contiguous read of geom, contiguous write of fc-folded gaussians
__global__ void gauss_k(const float4* __restrict__ geom,
                        const int* __restrict__ species,
                        const float* __restrict__ g_rs,
                        const float* __restrict__ g_inta,
                        const float* __restrict__ g_par,
                        float4* __restrict__ gauss,   // [2E] = [E][8] floats
                        int E)
{
    __shared__ float s_rs[32], s_in[32], s_pa[32];
    int tid = threadIdx.x;
    if (tid < 32) {
        s_rs[tid] = g_rs[tid];
        s_in[tid] = g_inta[tid];
        s_pa[tid] = g_par[tid];
    }
    __syncthreads();
    int s = blockIdx.x * blockDim.x + tid;
    if (s >= E) return;
    float4 G = geom[s];
    float r = sqrtf(G.x*G.x + G.y*G.y + G.z*G.z);
    float fcb = 0.5f * cosf(r * 0.6283185307179586f) + 0.5f;   // pi/5
    float fc  = fcb * fcb;
    int sb = species[__float_as_int(G.w)] * NW;
    float g[NW];
    #pragma unroll
    for (int w = 0; w < NW; ++w) {
        float dr = r - s_rs[sb + w];
        g[w] = __expf(-s_in[sb + w] * dr * dr) * s_pa[sb + w] * fc;
    }
    gauss[2*s+0] = make_float4(g[0], g[1], g[2], g[3]);
    gauss[2*s+1] = make_float4(g[4], g[5], g[6], g[7]);
}

// ---------------- fused per-atom pass: ONE WAVE (64 threads) per atom ----------------
// Lane handles features f=lane and f=lane+64 (f1 valid for lane<40).
// Single-wave block: barriers are near-free; 20-30 atom-waves/CU hide latency.
template<bool HASOUT, bool MLP>
__global__ __launch_bounds__(64)
void atom_pass(const float4* __restrict__ geom,
               const float4* __restrict__ gauss4,  // [E][2] float4, fc-folded
               const int* __restrict__ rowptr,
               const float* __restrict__ outp_in,  // [A,24] if HASOUT
               const float* __restrict__ w1, const float* __restrict__ b1,
               const float* __restrict__ w2, const float* __restrict__ b2,
               float* __restrict__ out,            // [A,24]: mlp out (MLP) or density
               int A)
{
    __shared__ __align__(16) float smem[CH * (ANG_S + OG_S)];   // 48*39*4 = 7488 B
    float* ls_ang = smem;                 // [CH][13]
    float* ls_og  = smem + CH * ANG_S;    // [CH][26] (24 used)
    // tail aliases (K-loop LDS dead after the post-loop barrier):
    float* orb_s = smem;                  // [104]
    float* dvec  = smem + 104;            // [24]
    float* tvec  = smem + 128;            // [128]

    int lane = threadIdx.x;
    int a = blockIdx.x;
    int s0 = rowptr[a], s1 = rowptr[a+1];

    int p0 = lane >> 3, w = lane & 7;
    int ip0 = (p0 == 0) ? 0 : ((p0 < 4) ? 1 : 2);
    int og0 = ip0 * NW + w;
    int p1 = p0 + 8;                      // feature f1 = lane+64 (valid lane<40)
    int og1 = 2 * NW + w;

    float acc0 = 0.0f, acc1 = 0.0f;

    for (int s = s0; s < s1; s += CH) {
        int m = min(CH, s1 - s);
        if (lane < m) {
            float4 G = gauss4[2*(s + lane)];
            float4 H = gauss4[2*(s + lane) + 1];
            float go[NW] = { G.x, G.y, G.z, G.w, H.x, H.y, H.z, H.w };
            float4 D = geom[s + lane];
            float ax = D.x, ay = D.y, az = D.z;

            float* ar = ls_ang + lane * ANG_S;
            ar[0]  = 1.0f;
            ar[1]  = ax;    ar[2]  = ay;    ar[3]  = az;
            ar[4]  = ax*ax; ar[5]  = ax*ay; ar[6]  = ax*az;
            ar[7]  = ay*ax; ar[8]  = ay*ay; ar[9]  = ay*az;
            ar[10] = az*ax; ar[11] = az*ay; ar[12] = az*az;

            float2* ogr = (float2*)(ls_og + lane * OG_S);
            if (HASOUT) {
                const float4* orow = (const float4*)(outp_in + (size_t)__float_as_int(D.w) * NATOM_FEAT);
                float4 o0 = orow[0], o1 = orow[1], o2 = orow[2];
                float4 o3 = orow[3], o4 = orow[4], o5 = orow[5];
                ogr[0]  = make_float2(go[0]*o0.x, go[1]*o0.y);
                ogr[1]  = make_float2(go[2]*o0.z, go[3]*o0.w);
                ogr[2]  = make_float2(go[4]*o1.x, go[5]*o1.y);
                ogr[3]  = make_float2(go[6]*o1.z, go[7]*o1.w);
                ogr[4]  = make_float2(go[0]*o2.x, go[1]*o2.y);
                ogr[5]  = make_float2(go[2]*o2.z, go[3]*o2.w);
                ogr[6]  = make_float2(go[4]*o3.x, go[5]*o3.y);
                ogr[7]  = make_float2(go[6]*o3.z, go[7]*o3.w);
                ogr[8]  = make_float2(go[0]*o4.x, go[1]*o4.y);
                ogr[9]  = make_float2(go[2]*o4.z, go[3]*o4.w);
                ogr[10] = make_float2(go[4]*o5.x, go[5]*o5.y);
                ogr[11] = make_float2(go[6]*o5.z, go[7]*o5.w);
            } else {
                #pragma unroll
                for (int cc = 0; cc < 12; ++cc)
                    ogr[cc] = make_float2(go[(2*cc) & 7], go[(2*cc+1) & 7]);
            }
        }
        __syncthreads();
        for (int j = 0; j < m; ++j) {
            float a0 = ls_ang[j * ANG_S + p0];
            float a1 = ls_ang[j * ANG_S + p1];   // lane>=40 reads in-bounds garbage, discarded
            float o0 = ls_og[j * OG_S + og0];
            float o1 = ls_og[j * OG_S + og1];
            acc0 += a0 * o0;
            acc1 += a1 * o1;
        }
        __syncthreads();
    }

    // orbital^2 -> aliased LDS (K-loop LDS dead after barrier above)
    orb_s[lane] = acc0 * acc0;
    if (lane < 40) orb_s[64 + lane] = acc1 * acc1;
    __syncthreads();

    if (lane < NATOM_FEAT) {
        int i = lane >> 3, ww = lane & 7;
        float sum;
        if (i == 0) {
            sum = orb_s[ww];
        } else if (i == 1) {
            sum = orb_s[NW + ww] + orb_s[2*NW + ww] + orb_s[3*NW + ww];
        } else {
            sum = 0.0f;
            #pragma unroll
            for (int q = 4; q < PORI; ++q) sum += orb_s[q*NW + ww];
        }
        if (MLP) dvec[lane] = sum;
        else     out[(size_t)a * NATOM_FEAT + lane] = sum;
    }

    if (MLP) {
        __syncthreads();
        // phase B: lane handles hidden units h=lane and h=lane+64
        float h0 = b1[lane], h1 = b1[lane + 64];
        #pragma unroll
        for (int j = 0; j < NATOM_FEAT; ++j) {
            float d = dvec[j];                       // broadcast
            h0 += d * w1[j * HID + lane];            // coalesced, L1-hot
            h1 += d * w1[j * HID + lane + 64];
        }
        float e0 = __expf(2.0f * h0), e1 = __expf(2.0f * h1);
        tvec[lane]      = 1.0f - 2.0f / (e0 + 1.0f);
        tvec[lane + 64] = 1.0f - 2.0f / (e1 + 1.0f);
        __syncthreads();
        // phase C: lanes 0..47 = (j = lane%24, h-half = lane/24); combine via shuffle
        int j  = (lane < 24) ? lane : lane - 24;
        int hb = (lane < 24) ? 0 : 64;
        float part = 0.0f;
        if (lane < 48) {
            #pragma unroll 8
            for (int h = 0; h < 64; ++h)
                part += tvec[hb + h] * w2[(hb + h) * NATOM_FEAT + j];
        }
        float other = __shfl(part, lane + 24);
        if (lane < NATOM_FEAT)
            out[(size_t)a * NATOM_FEAT + lane] = b2[lane] + part + other;
    }
}

extern "C" void kernel_launch(void* const* d_in, const int* in_sizes, int n_in,
                              void* d_out, int out_size, void* d_ws, size_t ws_size,
                              hipStream_t stream)
{
    const float* cart    = (const float*)d_in[0];
    const int*   nl      = (const int*)d_in[1];
    const float* shifts  = (const float*)d_in[2];
    const int*   species = (const int*)d_in[3];
    const float* rs      = (const float*)d_in[4];
    const float* inta    = (const float*)d_in[5];
    const float* params  = (const float*)d_in[6];
    const float* w1_0 = (const float*)d_in[7];
    const float* b1_0 = (const float*)d_in[8];
    const float* w2_0 = (const float*)d_in[9];
    const float* b2_0 = (const float*)d_in[10];
    const float* w1_1 = (const float*)d_in[11];
    const float* b1_1 = (const float*)d_in[12];
    const float* w2_1 = (const float*)d_in[13];
    const float* b2_1 = (const float*)d_in[14];

    const int A = in_sizes[0] / 3;
    const int E = in_sizes[1] / 2;

    // workspace layout — 16B-aligned arrays first
    char* ws = (char*)d_ws;
    float4* geom  = (float4*)ws;              ws += (size_t)E * 16;
    float4* gauss = (float4*)ws;              ws += (size_t)E * 32;
    int*   counts = (int*)ws;                 ws += (size_t)A * 4;
    int*   rowptr = (int*)ws;                 ws += (size_t)(A + 1) * 4;
    float* outpA  = (float*)ws;               ws += (size_t)A * NATOM_FEAT * 4;
    float* outpB  = (float*)ws;               ws += (size_t)A * NATOM_FEAT * 4;
    float* dout   = (float*)d_out;

    const int BLK = 256;
    const int gridE = (E + BLK - 1) / BLK;
    const int gridA = (A + BLK - 1) / BLK;

    // ---- CSR build + per-edge precompute (once) ----
    zero_k<<<gridA, BLK, 0, stream>>>(counts, A);
    csr_count<<<gridE, BLK, 0, stream>>>(nl, counts, E);
    csr_scan<<<1, SCAN_T, 0, stream>>>(counts, rowptr, A);
    csr_fill<<<gridE, BLK, 0, stream>>>(nl, rowptr, counts, cart, shifts, geom, E);
    gauss_k<<<gridE, BLK, 0, stream>>>(geom, species, rs, inta, params, gauss, E);

    // ---- pass 0 (+ MLP0) -> outpA ----
    atom_pass<false, true><<<A, 64, 0, stream>>>(geom, gauss, rowptr,
                                                 nullptr, w1_0, b1_0, w2_0, b2_0, outpA, A);
    // ---- pass 1 (+ MLP1) -> outpB ----
    atom_pass<true, true><<<A, 64, 0, stream>>>(geom, gauss, rowptr,
                                                outpA, w1_1, b1_1, w2_1, b2_1, outpB, A);
    // ---- pass 2 (density only) -> d_out ----
    atom_pass<true, false><<<A, 64, 0, stream>>>(geom, gauss, rowptr,
                                                 outpB, nullptr, nullptr, nullptr, nullptr, dout, A);
}